// Round 5
// baseline (196.002 us; speedup 1.0000x reference)
//
#include <hip/hip_runtime.h>

// ---------------------------------------------------------------------------
// MultiHeadAttention (B=2, T=2048, D=1024, NH=16, hd=64) with ALiBi + causal.
// r5: attention = r3's proven per-wave kernel, scaled to 8 waves / 128 q-rows
// per block sharing the staged K/V tiles (halves K/V refetch). Wave-uniform
// skip for the one fully-masked tile of the lower waves. All other kernels
// byte-identical to r3 (passed).
// ---------------------------------------------------------------------------

using f32x4  = __attribute__((ext_vector_type(4))) float;
using bf16x8 = __attribute__((ext_vector_type(8))) short;
typedef unsigned short u16;
using u16x4 = __attribute__((ext_vector_type(4))) u16;
using u32x4 = __attribute__((ext_vector_type(4))) unsigned int;

#define T_SEQ  2048
#define NHEAD  16
#define HDIM   64
#define DMODEL 1024
#define MROWS  4096   // B*T

#define LOG2E 1.4426950408889634f

__device__ __forceinline__ u16 f2bf(float f) {
  union { float f; unsigned u; } v; v.f = f;
  return (u16)((v.u + 0x7fffu + ((v.u >> 16) & 1u)) >> 16);  // RNE
}

__device__ __forceinline__ unsigned cvt_pk_bf16(float lo, float hi) {
  unsigned r;
  asm("v_cvt_pk_bf16_f32 %0, %1, %2" : "=v"(r) : "v"(lo), "v"(hi));
  return r;
}

__device__ __forceinline__ void gl_lds16(const u16* g, u16* l) {
  __builtin_amdgcn_global_load_lds(
      (const __attribute__((address_space(1))) unsigned int*)g,
      (__attribute__((address_space(3))) unsigned int*)l, 16, 0, 0);
}

// ---------------------------------------------------------------------------
__global__ __launch_bounds__(256) void cvt_bf16(const float* __restrict__ src,
                                                u16* __restrict__ dst, int n) {
  int i = (blockIdx.x * 256 + threadIdx.x) * 4;
  if (i < n) {
    const float4 v = *reinterpret_cast<const float4*>(src + i);
    u16x4 o;
    o.x = f2bf(v.x); o.y = f2bf(v.y); o.z = f2bf(v.z); o.w = f2bf(v.w);
    *reinterpret_cast<u16x4*>(dst + i) = o;
  }
}

// all four weights are 1M elements; dst regions contiguous
__global__ __launch_bounds__(256) void cvt_w4(
    const float* __restrict__ w0, const float* __restrict__ w1,
    const float* __restrict__ w2, const float* __restrict__ w3,
    u16* __restrict__ dst) {
  const float* src = (blockIdx.y == 0) ? w0 : (blockIdx.y == 1) ? w1
                   : (blockIdx.y == 2) ? w2 : w3;
  u16* d = dst + (size_t)blockIdx.y * 1048576;
  int i = (blockIdx.x * 256 + threadIdx.x) * 4;
  const float4 v = *reinterpret_cast<const float4*>(src + i);
  u16x4 o;
  o.x = f2bf(v.x); o.y = f2bf(v.y); o.z = f2bf(v.z); o.w = f2bf(v.w);
  *reinterpret_cast<u16x4*>(d + i) = o;
}

// ---------------------------------------------------------------------------
// Fused QKV projection (m97 structure, unchanged from r3 -- verified).
__global__ __launch_bounds__(256) void qkv_gemm(
    const u16* __restrict__ xb,
    const u16* __restrict__ wq, const u16* __restrict__ wk, const u16* __restrict__ wv,
    const float* __restrict__ bq, const float* __restrict__ bk, const float* __restrict__ bv,
    u16* __restrict__ q_ws, u16* __restrict__ k_ws, u16* __restrict__ vt_ws)
{
  const int K = DMODEL;
  const int z = blockIdx.z;
  const u16*   W    = (z == 0) ? wq : (z == 1) ? wk : wv;
  const float* bias = (z == 0) ? bq : (z == 1) ? bk : bv;
  const int bm = blockIdx.y, bn = blockIdx.x;
  const int tid = threadIdx.x;
  const int w = tid >> 6, lane = tid & 63, g = lane >> 4, c = lane & 15;
  const int wm = w >> 1, wn = w & 1;

  __shared__ u16 SM[2][128][64];

  f32x4 zero4 = {0.f, 0.f, 0.f, 0.f};
  f32x4 acc[4][4];
#pragma unroll
  for (int m = 0; m < 4; ++m)
#pragma unroll
    for (int n = 0; n < 4; ++n) acc[m][n] = zero4;

  int rr[4], cswz[4];
#pragma unroll
  for (int j = 0; j < 4; ++j) {
    int chunk = tid + 256 * j;
    rr[j] = chunk >> 3;
    cswz[j] = ((chunk & 7) ^ (rr[j] & 7)) * 8;
  }

  for (int k0 = 0; k0 < K; k0 += 64) {
#pragma unroll
    for (int j = 0; j < 4; ++j) {
      int chunk = tid + 256 * j;
      gl_lds16(xb + (size_t)(bm * 128 + rr[j]) * K + k0 + cswz[j],
               &SM[0][0][0] + chunk * 8);
      gl_lds16(W + (size_t)(bn * 128 + rr[j]) * K + k0 + cswz[j],
               &SM[1][0][0] + chunk * 8);
    }
    __syncthreads();
#pragma unroll
    for (int kk = 0; kk < 2; ++kk) {
      bf16x8 af[4], bfr[4];
#pragma unroll
      for (int m = 0; m < 4; ++m) {
        int row = wm * 64 + m * 16 + c;
        af[m] = *reinterpret_cast<const bf16x8*>(
            &SM[0][row][(kk * 32 + g * 8) ^ ((row & 7) * 8)]);
      }
#pragma unroll
      for (int n = 0; n < 4; ++n) {
        int row = wn * 64 + n * 16 + c;
        bfr[n] = *reinterpret_cast<const bf16x8*>(
            &SM[1][row][(kk * 32 + g * 8) ^ ((row & 7) * 8)]);
      }
#pragma unroll
      for (int m = 0; m < 4; ++m)
#pragma unroll
        for (int n = 0; n < 4; ++n)
          acc[m][n] = __builtin_amdgcn_mfma_f32_16x16x32_bf16(af[m], bfr[n], acc[m][n], 0, 0, 0);
    }
    __syncthreads();
  }

  const float rs = 0.1767766953f;          // 1024^-0.25
  const float qs = rs * LOG2E;

  if (z == 2) {
    u16* tr = &SM[0][0][0];
    const int bb = (bm * 128) >> 11;
    const int t_base = (bm * 128) & (T_SEQ - 1);
#pragma unroll
    for (int hh = 0; hh < 2; ++hh) {
      __syncthreads();
      if (wn == hh) {
#pragma unroll
        for (int n = 0; n < 4; ++n) {
          float bv_ = bias[bn * 128 + wn * 64 + n * 16 + c];
#pragma unroll
          for (int m = 0; m < 4; ++m) {
#pragma unroll
            for (int i = 0; i < 4; ++i) {
              tr[(n * 16 + c) * 136 + wm * 64 + m * 16 + g * 4 + i] =
                  f2bf(acc[m][n][i] + bv_);
            }
          }
        }
      }
      __syncthreads();
#pragma unroll
      for (int rep = 0; rep < 4; ++rep) {
        int idx = tid + rep * 256;
        int dr = idx >> 4, ch = idx & 15;
        bf16x8 vv = *reinterpret_cast<const bf16x8*>(&tr[dr * 136 + ch * 8]);
        int d_glob = bn * 128 + hh * 64 + dr;
        int head = d_glob >> 6, dd = d_glob & 63;
        *reinterpret_cast<bf16x8*>(
            vt_ws + (((size_t)(bb * NHEAD + head) * HDIM + dd) * T_SEQ) + t_base + ch * 8) = vv;
      }
    }
  } else {
    u16* dst = (z == 0) ? q_ws : k_ws;
    const float sc = (z == 0) ? qs : rs;
#pragma unroll
    for (int m = 0; m < 4; ++m) {
      int mrow_base = bm * 128 + wm * 64 + m * 16 + g * 4;
#pragma unroll
      for (int n = 0; n < 4; ++n) {
        int n_idx = bn * 128 + wn * 64 + n * 16 + c;
        float bv_ = bias[n_idx];
        int head = n_idx >> 6, d = n_idx & 63;
#pragma unroll
        for (int i = 0; i < 4; ++i) {
          int mrow = mrow_base + i;
          int b = mrow >> 11, t = mrow & (T_SEQ - 1);
          dst[((size_t)(b * NHEAD + head) * T_SEQ + t) * HDIM + d] =
              f2bf((acc[m][n][i] + bv_) * sc);
        }
      }
    }
  }
}

// ---------------------------------------------------------------------------
// Flash attention r5: 8 waves / 128 q-rows per block share double-buffered
// 64-kv K/V LDS tiles. Per-wave compute is r3's proven code verbatim; the
// only additions: wave-uniform skip (w_skip) and per-wave edge tile.
__global__ __launch_bounds__(512, 6) void attn_fused(
    const u16* __restrict__ Q, const u16* __restrict__ Kk,
    const u16* __restrict__ VT, u16* __restrict__ O)
{
  const int tid = threadIdx.x;
  const int w = tid >> 6;
  const int lane = tid & 63;
  const int g = lane >> 4, c = lane & 15;
  const int qb = gridDim.x - 1 - blockIdx.x;   // heavy blocks first
  const int q0 = qb * 128;
  const int bh = blockIdx.y;
  const int h = bh & (NHEAD - 1), b = bh >> 4;
  const float slope2 = exp2f(-0.5f * (float)(h + 1)) * LOG2E;
  const u16* Qp = Q  + (size_t)bh * T_SEQ * HDIM;
  const u16* Kp = Kk + (size_t)bh * T_SEQ * HDIM;
  const u16* Vp = VT + (size_t)bh * HDIM * T_SEQ;
  const int qrow = q0 + w * 16;                // 8 waves cover 128 q rows
  const int w_skip = (w >= 4) ? 0 : 1;         // lower waves: tile 0 all-future

  __shared__ u16 KB[2][64][64];
  __shared__ u16 VB[2][64][64];

  bf16x8 qf0 = *reinterpret_cast<const bf16x8*>(Qp + (size_t)(qrow + c) * HDIM + g * 8);
  bf16x8 qf1 = *reinterpret_cast<const bf16x8*>(Qp + (size_t)(qrow + c) * HDIM + 32 + g * 8);

  // staging: 512 threads x 16B = one full 64x64 bf16 tile per call
  const int s_r0 = tid >> 3;                    // 0..63
  const int s_c0 = ((tid & 7) ^ (s_r0 & 7)) * 8;  // inverse-swizzled source col

  const int nt = 2 * qb + 2;   // kv tiles: q0+64, q0, q0-64, ..., 0

  {
    const int kv0 = q0 + 64;
    gl_lds16(Kp + (size_t)(kv0 + s_r0) * HDIM + s_c0, &KB[0][0][0] + tid * 8);
    gl_lds16(Vp + (size_t)s_r0 * T_SEQ + kv0 + s_c0, &VB[0][0][0] + tid * 8);
  }
  __syncthreads();

  f32x4 zero4 = {0.f, 0.f, 0.f, 0.f};
  f32x4 o[4];
#pragma unroll
  for (int dg = 0; dg < 4; ++dg) o[dg] = zero4;
  float mrun = -3.0e38f, lrun = 0.f;

  for (int t = 0; t < nt; ++t) {
    const u16* kb = &KB[t & 1][0][0];
    const u16* vb = &VB[t & 1][0][0];

    // issue next-tile stage (in flight during this tile's compute)
    if (t + 1 < nt) {
      const int kvn = q0 - 64 * t;
      gl_lds16(Kp + (size_t)(kvn + s_r0) * HDIM + s_c0, &KB[(t + 1) & 1][0][0] + tid * 8);
      gl_lds16(Vp + (size_t)s_r0 * T_SEQ + kvn + s_c0, &VB[(t + 1) & 1][0][0] + tid * 8);
    }

    if (t >= w_skip) {
      const int kv0 = q0 + 64 - 64 * t;

      // --- QK^T (swapped): lane holds q=c, kv = 16jj + 4g + i ---
      f32x4 s[4];
#pragma unroll
      for (int jj = 0; jj < 4; ++jj) {
        const int r = jj * 16 + c;
        bf16x8 k0 = *reinterpret_cast<const bf16x8*>(kb + r * 64 + ((g ^ (r & 7)) * 8));
        bf16x8 k1 = *reinterpret_cast<const bf16x8*>(kb + r * 64 + (((4 + g) ^ (r & 7)) * 8));
        f32x4 z4 = zero4;
        z4 = __builtin_amdgcn_mfma_f32_16x16x32_bf16(k0, qf0, z4, 0, 0, 0);
        z4 = __builtin_amdgcn_mfma_f32_16x16x32_bf16(k1, qf1, z4, 0, 0, 0);
        s[jj] = z4;
      }

      // --- ALiBi bias (+ causal mask only on this wave's diagonal tile) ---
      const int kbase = kv0 + 4 * g - (qrow + c);   // kv - q at (jj=0,i=0)
      float mt = -3.0e38f;
      if (t == w_skip) {
#pragma unroll
        for (int jj = 0; jj < 4; ++jj)
#pragma unroll
          for (int i = 0; i < 4; ++i) {
            int rel = kbase + 16 * jj + i;
            float sv = s[jj][i] + slope2 * (float)rel;
            if (rel > 0) sv = -3.0e38f;
            s[jj][i] = sv;
            mt = fmaxf(mt, sv);
          }
      } else {
#pragma unroll
        for (int jj = 0; jj < 4; ++jj)
#pragma unroll
          for (int i = 0; i < 4; ++i) {
            float sv = s[jj][i] + slope2 * (float)(kbase + 16 * jj + i);
            s[jj][i] = sv;
            mt = fmaxf(mt, sv);
          }
      }
      mt = fmaxf(mt, __shfl_xor(mt, 16, 64));
      mt = fmaxf(mt, __shfl_xor(mt, 32, 64));

      // --- defer-max (T13): skip rescale while mt <= mrun + 8 nats ---
      if (!__all(mt <= mrun + 11.5416f)) {
        float mnew = fmaxf(mrun, mt);
        float alpha = __builtin_amdgcn_exp2f(mrun - mnew);
        mrun = mnew;
        lrun *= alpha;
        float ar[4];
#pragma unroll
        for (int i = 0; i < 4; ++i) ar[i] = __shfl(alpha, g * 4 + i, 64);
#pragma unroll
        for (int dg = 0; dg < 4; ++dg)
#pragma unroll
          for (int i = 0; i < 4; ++i) o[dg][i] *= ar[i];
      }

      // --- P = exp2(s - mrun), row-sum, pack to bf16 (cvt_pk) ---
      float p[16];
      float rsum = 0.f;
#pragma unroll
      for (int jj = 0; jj < 4; ++jj)
#pragma unroll
        for (int i = 0; i < 4; ++i) {
          float e = __builtin_amdgcn_exp2f(s[jj][i] - mrun);
          rsum += e;
          p[jj * 4 + i] = e;
        }
      union { bf16x8 v; u32x4 u; } P0, P1;
#pragma unroll
      for (int k = 0; k < 4; ++k) {
        P0.u[k] = cvt_pk_bf16(p[2 * k], p[2 * k + 1]);
        P1.u[k] = cvt_pk_bf16(p[8 + 2 * k], p[8 + 2 * k + 1]);
      }
      rsum += __shfl_xor(rsum, 16, 64);
      rsum += __shfl_xor(rsum, 32, 64);
      lrun += rsum;

      // --- PV: V fragments from swizzled LDS (permuted-k matches P) ---
#pragma unroll
      for (int dg = 0; dg < 4; ++dg) {
        const int vr = dg * 16 + c;
        const int vbase = vr * 64 + (g & 1) * 4;
        const int sw = vr & 7;
        short4 a0 = *reinterpret_cast<const short4*>(vb + vbase + (((g >> 1) + 0) ^ sw) * 8);
        short4 a1 = *reinterpret_cast<const short4*>(vb + vbase + (((g >> 1) + 2) ^ sw) * 8);
        short4 a2 = *reinterpret_cast<const short4*>(vb + vbase + (((g >> 1) + 4) ^ sw) * 8);
        short4 a3 = *reinterpret_cast<const short4*>(vb + vbase + (((g >> 1) + 6) ^ sw) * 8);
        bf16x8 vf0, vf1;
#pragma unroll
        for (int e = 0; e < 4; ++e) {
          vf0[e] = a0[e]; vf0[4 + e] = a1[e];
          vf1[e] = a2[e]; vf1[4 + e] = a3[e];
        }
        o[dg] = __builtin_amdgcn_mfma_f32_16x16x32_bf16(P0.v, vf0, o[dg], 0, 0, 0);
        o[dg] = __builtin_amdgcn_mfma_f32_16x16x32_bf16(P1.v, vf1, o[dg], 0, 0, 0);
      }
    }

    __syncthreads();   // all waves: drains stage(t+1) + LDS reads
  }

  // epilogue: divide by l (per output row q = g*4+i) and store
  float rl[4];
#pragma unroll
  for (int i = 0; i < 4; ++i) {
    float li = __shfl(lrun, g * 4 + i, 64);
    rl[i] = 1.0f / li;
  }
#pragma unroll
  for (int dg = 0; dg < 4; ++dg) {
#pragma unroll
    for (int i = 0; i < 4; ++i) {
      int qi = qrow + g * 4 + i;
      O[((size_t)b * T_SEQ + qi) * DMODEL + h * HDIM + dg * 16 + c] =
          f2bf(o[dg][i] * rl[i]);
    }
  }
}

// ---------------------------------------------------------------------------
// Output projection: out = ao @ Wp^T + bp (fp32 out). m97 GEMM core.
__global__ __launch_bounds__(256) void out_gemm(
    const u16* __restrict__ ao, const u16* __restrict__ wp,
    const float* __restrict__ bp, float* __restrict__ out)
{
  const int K = DMODEL;
  const int bm = blockIdx.y, bn = blockIdx.x;
  const int tid = threadIdx.x;
  const int w = tid >> 6, lane = tid & 63, g = lane >> 4, c = lane & 15;
  const int wm = w >> 1, wn = w & 1;

  __shared__ u16 SM[2][128][64];

  f32x4 zero4 = {0.f, 0.f, 0.f, 0.f};
  f32x4 acc[4][4];
#pragma unroll
  for (int m = 0; m < 4; ++m)
#pragma unroll
    for (int n = 0; n < 4; ++n) acc[m][n] = zero4;

  int rr[4], cswz[4];
#pragma unroll
  for (int j = 0; j < 4; ++j) {
    int chunk = tid + 256 * j;
    rr[j] = chunk >> 3;
    cswz[j] = ((chunk & 7) ^ (rr[j] & 7)) * 8;
  }

  for (int k0 = 0; k0 < K; k0 += 64) {
#pragma unroll
    for (int j = 0; j < 4; ++j) {
      int chunk = tid + 256 * j;
      gl_lds16(ao + (size_t)(bm * 128 + rr[j]) * K + k0 + cswz[j],
               &SM[0][0][0] + chunk * 8);
      gl_lds16(wp + (size_t)(bn * 128 + rr[j]) * K + k0 + cswz[j],
               &SM[1][0][0] + chunk * 8);
    }
    __syncthreads();
#pragma unroll
    for (int kk = 0; kk < 2; ++kk) {
      bf16x8 af[4], bfr[4];
#pragma unroll
      for (int m = 0; m < 4; ++m) {
        int row = wm * 64 + m * 16 + c;
        af[m] = *reinterpret_cast<const bf16x8*>(
            &SM[0][row][(kk * 32 + g * 8) ^ ((row & 7) * 8)]);
      }
#pragma unroll
      for (int n = 0; n < 4; ++n) {
        int row = wn * 64 + n * 16 + c;
        bfr[n] = *reinterpret_cast<const bf16x8*>(
            &SM[1][row][(kk * 32 + g * 8) ^ ((row & 7) * 8)]);
      }
#pragma unroll
      for (int m = 0; m < 4; ++m)
#pragma unroll
        for (int n = 0; n < 4; ++n)
          acc[m][n] = __builtin_amdgcn_mfma_f32_16x16x32_bf16(af[m], bfr[n], acc[m][n], 0, 0, 0);
    }
    __syncthreads();
  }

#pragma unroll
  for (int m = 0; m < 4; ++m) {
    int mrow_base = bm * 128 + wm * 64 + m * 16 + g * 4;
#pragma unroll
    for (int n = 0; n < 4; ++n) {
      int n_idx = bn * 128 + wn * 64 + n * 16 + c;
      float bv_ = bp[n_idx];
#pragma unroll
      for (int i = 0; i < 4; ++i) {
        int mrow = mrow_base + i;
        out[(size_t)mrow * DMODEL + n_idx] = acc[m][n][i] + bv_;
      }
    }
  }
}

// ---------------------------------------------------------------------------
extern "C" void kernel_launch(void* const* d_in, const int* in_sizes, int n_in,
                              void* d_out, int out_size, void* d_ws, size_t ws_size,
                              hipStream_t stream) {
  const float* x  = (const float*)d_in[0];
  const float* Wq = (const float*)d_in[1];
  const float* bq = (const float*)d_in[2];
  const float* Wk = (const float*)d_in[3];
  const float* bk = (const float*)d_in[4];
  const float* Wv = (const float*)d_in[5];
  const float* bv = (const float*)d_in[6];
  const float* Wp = (const float*)d_in[7];
  const float* bp = (const float*)d_in[8];
  float* out = (float*)d_out;

  u16* ws    = (u16*)d_ws;
  u16* xb    = ws;                       // 4,194,304  (x as bf16)
  u16* wqb   = xb   + 4194304;           // 4 x 1,048,576 contiguous
  u16* wkb   = wqb  + 1048576;
  u16* wvb   = wkb  + 1048576;
  u16* wpb   = wvb  + 1048576;
  u16* q_ws  = wpb  + 1048576;           // [B,NH,T,hd] (scaled by rs*log2e)
  u16* k_ws  = q_ws + 4194304;           // [B,NH,T,hd] (scaled by rs)
  u16* vt_ws = k_ws + 4194304;           // [B,NH,hd,T]
  u16* ao    = vt_ws + 4194304;          // [B,T,D] attention output

  cvt_bf16<<<4096, 256, 0, stream>>>(x, xb, 4194304);
  cvt_w4<<<dim3(1024, 4), 256, 0, stream>>>(Wq, Wk, Wv, Wp, wqb);

  qkv_gemm<<<dim3(DMODEL / 128, MROWS / 128, 3), 256, 0, stream>>>(
      xb, wqb, wkb, wvb, bq, bk, bv, q_ws, k_ws, vt_ws);

  attn_fused<<<dim3(T_SEQ / 128, 2 * NHEAD), 512, 0, stream>>>(q_ws, k_ws, vt_ws, ao);

  out_gemm<<<dim3(DMODEL / 128, MROWS / 128), 256, 0, stream>>>(ao, wpb, bp, out);
}

// Round 6
// 152.809 us; speedup vs baseline: 1.2827x; 1.2827x over previous
//
#include <hip/hip_runtime.h>

// ---------------------------------------------------------------------------
// MultiHeadAttention (B=2, T=2048, D=1024, NH=16, hd=64) with ALiBi + causal.
// r6: attention = r3's proven 4-wave/64-q kernel wrapped in a triangular
// PAIRING loop: block j processes q-tiles (31-j) then (j) -> every block
// does exactly 33 kv-tiles, killing the per-CU load imbalance that capped
// occupancy at 19%. All other kernels byte-identical to r3 (passed, 173us).
// ---------------------------------------------------------------------------

using f32x4  = __attribute__((ext_vector_type(4))) float;
using bf16x8 = __attribute__((ext_vector_type(8))) short;
typedef unsigned short u16;
using u16x4 = __attribute__((ext_vector_type(4))) u16;
using u32x4 = __attribute__((ext_vector_type(4))) unsigned int;

#define T_SEQ  2048
#define NHEAD  16
#define HDIM   64
#define DMODEL 1024
#define MROWS  4096   // B*T

#define LOG2E 1.4426950408889634f

__device__ __forceinline__ u16 f2bf(float f) {
  union { float f; unsigned u; } v; v.f = f;
  return (u16)((v.u + 0x7fffu + ((v.u >> 16) & 1u)) >> 16);  // RNE
}

__device__ __forceinline__ unsigned cvt_pk_bf16(float lo, float hi) {
  unsigned r;
  asm("v_cvt_pk_bf16_f32 %0, %1, %2" : "=v"(r) : "v"(lo), "v"(hi));
  return r;
}

__device__ __forceinline__ void gl_lds16(const u16* g, u16* l) {
  __builtin_amdgcn_global_load_lds(
      (const __attribute__((address_space(1))) unsigned int*)g,
      (__attribute__((address_space(3))) unsigned int*)l, 16, 0, 0);
}

// ---------------------------------------------------------------------------
__global__ __launch_bounds__(256) void cvt_bf16(const float* __restrict__ src,
                                                u16* __restrict__ dst, int n) {
  int i = (blockIdx.x * 256 + threadIdx.x) * 4;
  if (i < n) {
    const float4 v = *reinterpret_cast<const float4*>(src + i);
    u16x4 o;
    o.x = f2bf(v.x); o.y = f2bf(v.y); o.z = f2bf(v.z); o.w = f2bf(v.w);
    *reinterpret_cast<u16x4*>(dst + i) = o;
  }
}

// all four weights are 1M elements; dst regions contiguous
__global__ __launch_bounds__(256) void cvt_w4(
    const float* __restrict__ w0, const float* __restrict__ w1,
    const float* __restrict__ w2, const float* __restrict__ w3,
    u16* __restrict__ dst) {
  const float* src = (blockIdx.y == 0) ? w0 : (blockIdx.y == 1) ? w1
                   : (blockIdx.y == 2) ? w2 : w3;
  u16* d = dst + (size_t)blockIdx.y * 1048576;
  int i = (blockIdx.x * 256 + threadIdx.x) * 4;
  const float4 v = *reinterpret_cast<const float4*>(src + i);
  u16x4 o;
  o.x = f2bf(v.x); o.y = f2bf(v.y); o.z = f2bf(v.z); o.w = f2bf(v.w);
  *reinterpret_cast<u16x4*>(d + i) = o;
}

// ---------------------------------------------------------------------------
// Fused QKV projection (m97 structure, unchanged from r3 -- verified).
__global__ __launch_bounds__(256) void qkv_gemm(
    const u16* __restrict__ xb,
    const u16* __restrict__ wq, const u16* __restrict__ wk, const u16* __restrict__ wv,
    const float* __restrict__ bq, const float* __restrict__ bk, const float* __restrict__ bv,
    u16* __restrict__ q_ws, u16* __restrict__ k_ws, u16* __restrict__ vt_ws)
{
  const int K = DMODEL;
  const int z = blockIdx.z;
  const u16*   W    = (z == 0) ? wq : (z == 1) ? wk : wv;
  const float* bias = (z == 0) ? bq : (z == 1) ? bk : bv;
  const int bm = blockIdx.y, bn = blockIdx.x;
  const int tid = threadIdx.x;
  const int w = tid >> 6, lane = tid & 63, g = lane >> 4, c = lane & 15;
  const int wm = w >> 1, wn = w & 1;

  __shared__ u16 SM[2][128][64];

  f32x4 zero4 = {0.f, 0.f, 0.f, 0.f};
  f32x4 acc[4][4];
#pragma unroll
  for (int m = 0; m < 4; ++m)
#pragma unroll
    for (int n = 0; n < 4; ++n) acc[m][n] = zero4;

  int rr[4], cswz[4];
#pragma unroll
  for (int j = 0; j < 4; ++j) {
    int chunk = tid + 256 * j;
    rr[j] = chunk >> 3;
    cswz[j] = ((chunk & 7) ^ (rr[j] & 7)) * 8;
  }

  for (int k0 = 0; k0 < K; k0 += 64) {
#pragma unroll
    for (int j = 0; j < 4; ++j) {
      int chunk = tid + 256 * j;
      gl_lds16(xb + (size_t)(bm * 128 + rr[j]) * K + k0 + cswz[j],
               &SM[0][0][0] + chunk * 8);
      gl_lds16(W + (size_t)(bn * 128 + rr[j]) * K + k0 + cswz[j],
               &SM[1][0][0] + chunk * 8);
    }
    __syncthreads();
#pragma unroll
    for (int kk = 0; kk < 2; ++kk) {
      bf16x8 af[4], bfr[4];
#pragma unroll
      for (int m = 0; m < 4; ++m) {
        int row = wm * 64 + m * 16 + c;
        af[m] = *reinterpret_cast<const bf16x8*>(
            &SM[0][row][(kk * 32 + g * 8) ^ ((row & 7) * 8)]);
      }
#pragma unroll
      for (int n = 0; n < 4; ++n) {
        int row = wn * 64 + n * 16 + c;
        bfr[n] = *reinterpret_cast<const bf16x8*>(
            &SM[1][row][(kk * 32 + g * 8) ^ ((row & 7) * 8)]);
      }
#pragma unroll
      for (int m = 0; m < 4; ++m)
#pragma unroll
        for (int n = 0; n < 4; ++n)
          acc[m][n] = __builtin_amdgcn_mfma_f32_16x16x32_bf16(af[m], bfr[n], acc[m][n], 0, 0, 0);
    }
    __syncthreads();
  }

  const float rs = 0.1767766953f;          // 1024^-0.25
  const float qs = rs * LOG2E;

  if (z == 2) {
    u16* tr = &SM[0][0][0];
    const int bb = (bm * 128) >> 11;
    const int t_base = (bm * 128) & (T_SEQ - 1);
#pragma unroll
    for (int hh = 0; hh < 2; ++hh) {
      __syncthreads();
      if (wn == hh) {
#pragma unroll
        for (int n = 0; n < 4; ++n) {
          float bv_ = bias[bn * 128 + wn * 64 + n * 16 + c];
#pragma unroll
          for (int m = 0; m < 4; ++m) {
#pragma unroll
            for (int i = 0; i < 4; ++i) {
              tr[(n * 16 + c) * 136 + wm * 64 + m * 16 + g * 4 + i] =
                  f2bf(acc[m][n][i] + bv_);
            }
          }
        }
      }
      __syncthreads();
#pragma unroll
      for (int rep = 0; rep < 4; ++rep) {
        int idx = tid + rep * 256;
        int dr = idx >> 4, ch = idx & 15;
        bf16x8 vv = *reinterpret_cast<const bf16x8*>(&tr[dr * 136 + ch * 8]);
        int d_glob = bn * 128 + hh * 64 + dr;
        int head = d_glob >> 6, dd = d_glob & 63;
        *reinterpret_cast<bf16x8*>(
            vt_ws + (((size_t)(bb * NHEAD + head) * HDIM + dd) * T_SEQ) + t_base + ch * 8) = vv;
      }
    }
  } else {
    u16* dst = (z == 0) ? q_ws : k_ws;
    const float sc = (z == 0) ? qs : rs;
#pragma unroll
    for (int m = 0; m < 4; ++m) {
      int mrow_base = bm * 128 + wm * 64 + m * 16 + g * 4;
#pragma unroll
      for (int n = 0; n < 4; ++n) {
        int n_idx = bn * 128 + wn * 64 + n * 16 + c;
        float bv_ = bias[n_idx];
        int head = n_idx >> 6, d = n_idx & 63;
#pragma unroll
        for (int i = 0; i < 4; ++i) {
          int mrow = mrow_base + i;
          int b = mrow >> 11, t = mrow & (T_SEQ - 1);
          dst[((size_t)(b * NHEAD + head) * T_SEQ + t) * HDIM + d] =
              f2bf((acc[m][n][i] + bv_) * sc);
        }
      }
    }
  }
}

// ---------------------------------------------------------------------------
// Flash attention r6: triangular-paired blocks. Block j handles q-tile (31-j)
// then q-tile (j): exactly 33 kv-tiles per block -> uniform load. Per-pass
// body is r3's proven code verbatim (LDS-staged double-buffered K/V, swapped
// QK^T register softmax, descending kv, defer-max).
__global__ __launch_bounds__(256, 4) void attn_fused(
    const u16* __restrict__ Q, const u16* __restrict__ Kk,
    const u16* __restrict__ VT, u16* __restrict__ O)
{
  const int tid = threadIdx.x;
  const int w = tid >> 6;
  const int lane = tid & 63;
  const int g = lane >> 4, c = lane & 15;
  const int j = blockIdx.x;                    // 0..15 (pair index)
  const int bh = blockIdx.y;
  const int h = bh & (NHEAD - 1), b = bh >> 4;
  const float slope2 = exp2f(-0.5f * (float)(h + 1)) * LOG2E;
  const u16* Qp = Q  + (size_t)bh * T_SEQ * HDIM;
  const u16* Kp = Kk + (size_t)bh * T_SEQ * HDIM;
  const u16* Vp = VT + (size_t)bh * HDIM * T_SEQ;

  __shared__ u16 KB[2][64][64];
  __shared__ u16 VB[2][64][64];

  // staging geometry: 256 threads x (2 K + 2 V) x 16B per tile
  const int s_r0 = tid >> 3;          // 0..31
  const int s_r1 = s_r0 + 32;         // 32..63 ((s_r1&7)==(s_r0&7))
  const int s_c0 = ((tid & 7) ^ (s_r0 & 7)) * 8;

  f32x4 zero4 = {0.f, 0.f, 0.f, 0.f};

  for (int pass = 0; pass < 2; ++pass) {
    const int qb = (pass == 0) ? (T_SEQ / 64 - 1 - j) : j;   // heavy then light
    const int q0 = qb * 64;
    const int qrow = q0 + w * 16;
    const int nt = qb + 1;

    bf16x8 qf0 = *reinterpret_cast<const bf16x8*>(Qp + (size_t)(qrow + c) * HDIM + g * 8);
    bf16x8 qf1 = *reinterpret_cast<const bf16x8*>(Qp + (size_t)(qrow + c) * HDIM + 32 + g * 8);

    // prologue: stage tile 0 (kv0 = q0, the diagonal tile) into buffer 0
    {
      u16* kb = &KB[0][0][0]; u16* vb = &VB[0][0][0];
      gl_lds16(Kp + (size_t)(q0 + s_r0) * HDIM + s_c0, kb + tid * 8);
      gl_lds16(Kp + (size_t)(q0 + s_r1) * HDIM + s_c0, kb + (tid + 256) * 8);
      gl_lds16(Vp + (size_t)s_r0 * T_SEQ + q0 + s_c0, vb + tid * 8);
      gl_lds16(Vp + (size_t)s_r1 * T_SEQ + q0 + s_c0, vb + (tid + 256) * 8);
    }
    __syncthreads();

    f32x4 o[4];
#pragma unroll
    for (int dg = 0; dg < 4; ++dg) o[dg] = zero4;
    float mrun = -3.0e38f, lrun = 0.f;

    for (int t = 0; t < nt; ++t) {
      const u16* kb = &KB[t & 1][0][0];
      const u16* vb = &VB[t & 1][0][0];

      // issue next-tile stage (in flight during this tile's compute)
      if (t + 1 < nt) {
        const int kvn = (nt - 2 - t) * 64;
        u16* kbn = &KB[(t + 1) & 1][0][0];
        u16* vbn = &VB[(t + 1) & 1][0][0];
        gl_lds16(Kp + (size_t)(kvn + s_r0) * HDIM + s_c0, kbn + tid * 8);
        gl_lds16(Kp + (size_t)(kvn + s_r1) * HDIM + s_c0, kbn + (tid + 256) * 8);
        gl_lds16(Vp + (size_t)s_r0 * T_SEQ + kvn + s_c0, vbn + tid * 8);
        gl_lds16(Vp + (size_t)s_r1 * T_SEQ + kvn + s_c0, vbn + (tid + 256) * 8);
      }

      const int kv0 = (nt - 1 - t) * 64;

      // --- QK^T (swapped): lane holds q=c, kv = 16jj + 4g + i ---
      f32x4 s[4];
#pragma unroll
      for (int jj = 0; jj < 4; ++jj) {
        const int r = jj * 16 + c;
        bf16x8 k0 = *reinterpret_cast<const bf16x8*>(kb + r * 64 + ((g ^ (r & 7)) * 8));
        bf16x8 k1 = *reinterpret_cast<const bf16x8*>(kb + r * 64 + (((4 + g) ^ (r & 7)) * 8));
        f32x4 z4 = zero4;
        z4 = __builtin_amdgcn_mfma_f32_16x16x32_bf16(k0, qf0, z4, 0, 0, 0);
        z4 = __builtin_amdgcn_mfma_f32_16x16x32_bf16(k1, qf1, z4, 0, 0, 0);
        s[jj] = z4;
      }

      // --- ALiBi bias (+ causal mask only on the diagonal tile t==0) ---
      const int kbase = kv0 + 4 * g - (qrow + c);   // kv - q at (jj=0,i=0)
      float mt = -3.0e38f;
      if (t == 0) {
#pragma unroll
        for (int jj = 0; jj < 4; ++jj)
#pragma unroll
          for (int i = 0; i < 4; ++i) {
            int rel = kbase + 16 * jj + i;
            float sv = s[jj][i] + slope2 * (float)rel;
            if (rel > 0) sv = -3.0e38f;
            s[jj][i] = sv;
            mt = fmaxf(mt, sv);
          }
      } else {
#pragma unroll
        for (int jj = 0; jj < 4; ++jj)
#pragma unroll
          for (int i = 0; i < 4; ++i) {
            float sv = s[jj][i] + slope2 * (float)(kbase + 16 * jj + i);
            s[jj][i] = sv;
            mt = fmaxf(mt, sv);
          }
      }
      mt = fmaxf(mt, __shfl_xor(mt, 16, 64));
      mt = fmaxf(mt, __shfl_xor(mt, 32, 64));

      // --- defer-max (T13): skip rescale while mt <= mrun + 8 nats ---
      if (!__all(mt <= mrun + 11.5416f)) {
        float mnew = fmaxf(mrun, mt);
        float alpha = __builtin_amdgcn_exp2f(mrun - mnew);
        mrun = mnew;
        lrun *= alpha;
        float ar[4];
#pragma unroll
        for (int i = 0; i < 4; ++i) ar[i] = __shfl(alpha, g * 4 + i, 64);
#pragma unroll
        for (int dg = 0; dg < 4; ++dg)
#pragma unroll
          for (int i = 0; i < 4; ++i) o[dg][i] *= ar[i];
      }

      // --- P = exp2(s - mrun), row-sum, pack to bf16 (cvt_pk) ---
      float p[16];
      float rsum = 0.f;
#pragma unroll
      for (int jj = 0; jj < 4; ++jj)
#pragma unroll
        for (int i = 0; i < 4; ++i) {
          float e = __builtin_amdgcn_exp2f(s[jj][i] - mrun);
          rsum += e;
          p[jj * 4 + i] = e;
        }
      union { bf16x8 v; u32x4 u; } P0, P1;
#pragma unroll
      for (int k = 0; k < 4; ++k) {
        P0.u[k] = cvt_pk_bf16(p[2 * k], p[2 * k + 1]);
        P1.u[k] = cvt_pk_bf16(p[8 + 2 * k], p[8 + 2 * k + 1]);
      }
      rsum += __shfl_xor(rsum, 16, 64);
      rsum += __shfl_xor(rsum, 32, 64);
      lrun += rsum;

      // --- PV: V fragments from swizzled LDS (permuted-k matches P) ---
#pragma unroll
      for (int dg = 0; dg < 4; ++dg) {
        const int vr = dg * 16 + c;
        const int vbase = vr * 64 + (g & 1) * 4;
        const int sw = vr & 7;
        short4 a0 = *reinterpret_cast<const short4*>(vb + vbase + (((g >> 1) + 0) ^ sw) * 8);
        short4 a1 = *reinterpret_cast<const short4*>(vb + vbase + (((g >> 1) + 2) ^ sw) * 8);
        short4 a2 = *reinterpret_cast<const short4*>(vb + vbase + (((g >> 1) + 4) ^ sw) * 8);
        short4 a3 = *reinterpret_cast<const short4*>(vb + vbase + (((g >> 1) + 6) ^ sw) * 8);
        bf16x8 vf0, vf1;
#pragma unroll
        for (int e = 0; e < 4; ++e) {
          vf0[e] = a0[e]; vf0[4 + e] = a1[e];
          vf1[e] = a2[e]; vf1[4 + e] = a3[e];
        }
        o[dg] = __builtin_amdgcn_mfma_f32_16x16x32_bf16(P0.v, vf0, o[dg], 0, 0, 0);
        o[dg] = __builtin_amdgcn_mfma_f32_16x16x32_bf16(P1.v, vf1, o[dg], 0, 0, 0);
      }

      __syncthreads();   // drains stage(t+1) [vmcnt] + our ds_reads [lgkmcnt]
    }

    // epilogue: divide by l (per output row q = g*4+i) and store
    float rl[4];
#pragma unroll
    for (int i = 0; i < 4; ++i) {
      float li = __shfl(lrun, g * 4 + i, 64);
      rl[i] = 1.0f / li;
    }
#pragma unroll
    for (int dg = 0; dg < 4; ++dg) {
#pragma unroll
      for (int i = 0; i < 4; ++i) {
        int qi = qrow + g * 4 + i;
        O[((size_t)b * T_SEQ + qi) * DMODEL + h * HDIM + dg * 16 + c] =
            f2bf(o[dg][i] * rl[i]);
      }
    }
  }
}

// ---------------------------------------------------------------------------
// Output projection: out = ao @ Wp^T + bp (fp32 out). m97 GEMM core.
__global__ __launch_bounds__(256) void out_gemm(
    const u16* __restrict__ ao, const u16* __restrict__ wp,
    const float* __restrict__ bp, float* __restrict__ out)
{
  const int K = DMODEL;
  const int bm = blockIdx.y, bn = blockIdx.x;
  const int tid = threadIdx.x;
  const int w = tid >> 6, lane = tid & 63, g = lane >> 4, c = lane & 15;
  const int wm = w >> 1, wn = w & 1;

  __shared__ u16 SM[2][128][64];

  f32x4 zero4 = {0.f, 0.f, 0.f, 0.f};
  f32x4 acc[4][4];
#pragma unroll
  for (int m = 0; m < 4; ++m)
#pragma unroll
    for (int n = 0; n < 4; ++n) acc[m][n] = zero4;

  int rr[4], cswz[4];
#pragma unroll
  for (int j = 0; j < 4; ++j) {
    int chunk = tid + 256 * j;
    rr[j] = chunk >> 3;
    cswz[j] = ((chunk & 7) ^ (rr[j] & 7)) * 8;
  }

  for (int k0 = 0; k0 < K; k0 += 64) {
#pragma unroll
    for (int j = 0; j < 4; ++j) {
      int chunk = tid + 256 * j;
      gl_lds16(ao + (size_t)(bm * 128 + rr[j]) * K + k0 + cswz[j],
               &SM[0][0][0] + chunk * 8);
      gl_lds16(wp + (size_t)(bn * 128 + rr[j]) * K + k0 + cswz[j],
               &SM[1][0][0] + chunk * 8);
    }
    __syncthreads();
#pragma unroll
    for (int kk = 0; kk < 2; ++kk) {
      bf16x8 af[4], bfr[4];
#pragma unroll
      for (int m = 0; m < 4; ++m) {
        int row = wm * 64 + m * 16 + c;
        af[m] = *reinterpret_cast<const bf16x8*>(
            &SM[0][row][(kk * 32 + g * 8) ^ ((row & 7) * 8)]);
      }
#pragma unroll
      for (int n = 0; n < 4; ++n) {
        int row = wn * 64 + n * 16 + c;
        bfr[n] = *reinterpret_cast<const bf16x8*>(
            &SM[1][row][(kk * 32 + g * 8) ^ ((row & 7) * 8)]);
      }
#pragma unroll
      for (int m = 0; m < 4; ++m)
#pragma unroll
        for (int n = 0; n < 4; ++n)
          acc[m][n] = __builtin_amdgcn_mfma_f32_16x16x32_bf16(af[m], bfr[n], acc[m][n], 0, 0, 0);
    }
    __syncthreads();
  }

#pragma unroll
  for (int m = 0; m < 4; ++m) {
    int mrow_base = bm * 128 + wm * 64 + m * 16 + g * 4;
#pragma unroll
    for (int n = 0; n < 4; ++n) {
      int n_idx = bn * 128 + wn * 64 + n * 16 + c;
      float bv_ = bp[n_idx];
#pragma unroll
      for (int i = 0; i < 4; ++i) {
        int mrow = mrow_base + i;
        out[(size_t)mrow * DMODEL + n_idx] = acc[m][n][i] + bv_;
      }
    }
  }
}

// ---------------------------------------------------------------------------
extern "C" void kernel_launch(void* const* d_in, const int* in_sizes, int n_in,
                              void* d_out, int out_size, void* d_ws, size_t ws_size,
                              hipStream_t stream) {
  const float* x  = (const float*)d_in[0];
  const float* Wq = (const float*)d_in[1];
  const float* bq = (const float*)d_in[2];
  const float* Wk = (const float*)d_in[3];
  const float* bk = (const float*)d_in[4];
  const float* Wv = (const float*)d_in[5];
  const float* bv = (const float*)d_in[6];
  const float* Wp = (const float*)d_in[7];
  const float* bp = (const float*)d_in[8];
  float* out = (float*)d_out;

  u16* ws    = (u16*)d_ws;
  u16* xb    = ws;                       // 4,194,304  (x as bf16)
  u16* wqb   = xb   + 4194304;           // 4 x 1,048,576 contiguous
  u16* wkb   = wqb  + 1048576;
  u16* wvb   = wkb  + 1048576;
  u16* wpb   = wvb  + 1048576;
  u16* q_ws  = wpb  + 1048576;           // [B,NH,T,hd] (scaled by rs*log2e)
  u16* k_ws  = q_ws + 4194304;           // [B,NH,T,hd] (scaled by rs)
  u16* vt_ws = k_ws + 4194304;           // [B,NH,hd,T]
  u16* ao    = vt_ws + 4194304;          // [B,T,D] attention output

  cvt_bf16<<<4096, 256, 0, stream>>>(x, xb, 4194304);
  cvt_w4<<<dim3(1024, 4), 256, 0, stream>>>(Wq, Wk, Wv, Wp, wqb);

  qkv_gemm<<<dim3(DMODEL / 128, MROWS / 128, 3), 256, 0, stream>>>(
      xb, wqb, wkb, wvb, bq, bk, bv, q_ws, k_ws, vt_ws);

  attn_fused<<<dim3(T_SEQ / 128, 2 * NHEAD), 256, 0, stream>>>(q_ws, k_ws, vt_ws, ao);

  out_gemm<<<dim3(DMODEL / 128, MROWS / 128), 256, 0, stream>>>(ao, wpb, bp, out);
}

// Round 7
// 121.166 us; speedup vs baseline: 1.6176x; 1.2612x over previous
//
#include <hip/hip_runtime.h>

// ---------------------------------------------------------------------------
// MultiHeadAttention (B=2, T=2048, D=1024, NH=16, hd=64) with ALiBi + causal.
// r7: GEMMs (qkv, out) upgraded to double-buffered 2-phase K-loop (stage t+1
// issued before compute t, one barrier per step) -- the same schedule that
// fixed attn in r3. LDS 64 KB (2 blocks/CU). Attention = r6's triangular-
// paired kernel verbatim. Converts verbatim.
// ---------------------------------------------------------------------------

using f32x4  = __attribute__((ext_vector_type(4))) float;
using bf16x8 = __attribute__((ext_vector_type(8))) short;
typedef unsigned short u16;
using u16x4 = __attribute__((ext_vector_type(4))) u16;
using u32x4 = __attribute__((ext_vector_type(4))) unsigned int;

#define T_SEQ  2048
#define NHEAD  16
#define HDIM   64
#define DMODEL 1024
#define MROWS  4096   // B*T

#define LOG2E 1.4426950408889634f

__device__ __forceinline__ u16 f2bf(float f) {
  union { float f; unsigned u; } v; v.f = f;
  return (u16)((v.u + 0x7fffu + ((v.u >> 16) & 1u)) >> 16);  // RNE
}

__device__ __forceinline__ unsigned cvt_pk_bf16(float lo, float hi) {
  unsigned r;
  asm("v_cvt_pk_bf16_f32 %0, %1, %2" : "=v"(r) : "v"(lo), "v"(hi));
  return r;
}

__device__ __forceinline__ void gl_lds16(const u16* g, u16* l) {
  __builtin_amdgcn_global_load_lds(
      (const __attribute__((address_space(1))) unsigned int*)g,
      (__attribute__((address_space(3))) unsigned int*)l, 16, 0, 0);
}

// ---------------------------------------------------------------------------
__global__ __launch_bounds__(256) void cvt_bf16(const float* __restrict__ src,
                                                u16* __restrict__ dst, int n) {
  int i = (blockIdx.x * 256 + threadIdx.x) * 4;
  if (i < n) {
    const float4 v = *reinterpret_cast<const float4*>(src + i);
    u16x4 o;
    o.x = f2bf(v.x); o.y = f2bf(v.y); o.z = f2bf(v.z); o.w = f2bf(v.w);
    *reinterpret_cast<u16x4*>(dst + i) = o;
  }
}

// all four weights are 1M elements; dst regions contiguous
__global__ __launch_bounds__(256) void cvt_w4(
    const float* __restrict__ w0, const float* __restrict__ w1,
    const float* __restrict__ w2, const float* __restrict__ w3,
    u16* __restrict__ dst) {
  const float* src = (blockIdx.y == 0) ? w0 : (blockIdx.y == 1) ? w1
                   : (blockIdx.y == 2) ? w2 : w3;
  u16* d = dst + (size_t)blockIdx.y * 1048576;
  int i = (blockIdx.x * 256 + threadIdx.x) * 4;
  const float4 v = *reinterpret_cast<const float4*>(src + i);
  u16x4 o;
  o.x = f2bf(v.x); o.y = f2bf(v.y); o.z = f2bf(v.z); o.w = f2bf(v.w);
  *reinterpret_cast<u16x4*>(d + i) = o;
}

// ---------------------------------------------------------------------------
// Fused QKV projection, r7: double-buffered 2-phase K-loop.
__global__ __launch_bounds__(256) void qkv_gemm(
    const u16* __restrict__ xb,
    const u16* __restrict__ wq, const u16* __restrict__ wk, const u16* __restrict__ wv,
    const float* __restrict__ bq, const float* __restrict__ bk, const float* __restrict__ bv,
    u16* __restrict__ q_ws, u16* __restrict__ k_ws, u16* __restrict__ vt_ws)
{
  const int K = DMODEL;
  const int z = blockIdx.z;
  const u16*   W    = (z == 0) ? wq : (z == 1) ? wk : wv;
  const float* bias = (z == 0) ? bq : (z == 1) ? bk : bv;
  const int bm = blockIdx.y, bn = blockIdx.x;
  const int tid = threadIdx.x;
  const int w = tid >> 6, lane = tid & 63, g = lane >> 4, c = lane & 15;
  const int wm = w >> 1, wn = w & 1;

  __shared__ u16 SM[2][2][128][64];   // [buf][A=0/B=1], 64 KB

  f32x4 zero4 = {0.f, 0.f, 0.f, 0.f};
  f32x4 acc[4][4];
#pragma unroll
  for (int m = 0; m < 4; ++m)
#pragma unroll
    for (int n = 0; n < 4; ++n) acc[m][n] = zero4;

  int rr[4], cswz[4];
#pragma unroll
  for (int j = 0; j < 4; ++j) {
    int chunk = tid + 256 * j;
    rr[j] = chunk >> 3;
    cswz[j] = ((chunk & 7) ^ (rr[j] & 7)) * 8;
  }

  // prologue: stage k0=0 into buf 0
#pragma unroll
  for (int j = 0; j < 4; ++j) {
    int chunk = tid + 256 * j;
    gl_lds16(xb + (size_t)(bm * 128 + rr[j]) * K + cswz[j],
             &SM[0][0][0][0] + chunk * 8);
    gl_lds16(W + (size_t)(bn * 128 + rr[j]) * K + cswz[j],
             &SM[0][1][0][0] + chunk * 8);
  }
  __syncthreads();

  for (int t = 0; t < 16; ++t) {
    const int buf = t & 1;
    // issue next K-step stage (in flight during this step's compute)
    if (t < 15) {
      const int k0 = (t + 1) * 64;
#pragma unroll
      for (int j = 0; j < 4; ++j) {
        int chunk = tid + 256 * j;
        gl_lds16(xb + (size_t)(bm * 128 + rr[j]) * K + k0 + cswz[j],
                 &SM[buf ^ 1][0][0][0] + chunk * 8);
        gl_lds16(W + (size_t)(bn * 128 + rr[j]) * K + k0 + cswz[j],
                 &SM[buf ^ 1][1][0][0] + chunk * 8);
      }
    }
#pragma unroll
    for (int kk = 0; kk < 2; ++kk) {
      bf16x8 af[4], bfr[4];
#pragma unroll
      for (int m = 0; m < 4; ++m) {
        int row = wm * 64 + m * 16 + c;
        af[m] = *reinterpret_cast<const bf16x8*>(
            &SM[buf][0][row][(kk * 32 + g * 8) ^ ((row & 7) * 8)]);
      }
#pragma unroll
      for (int n = 0; n < 4; ++n) {
        int row = wn * 64 + n * 16 + c;
        bfr[n] = *reinterpret_cast<const bf16x8*>(
            &SM[buf][1][row][(kk * 32 + g * 8) ^ ((row & 7) * 8)]);
      }
#pragma unroll
      for (int m = 0; m < 4; ++m)
#pragma unroll
        for (int n = 0; n < 4; ++n)
          acc[m][n] = __builtin_amdgcn_mfma_f32_16x16x32_bf16(af[m], bfr[n], acc[m][n], 0, 0, 0);
    }
    __syncthreads();   // drains stage(t+1) [vmcnt] + this step's ds_reads
  }

  const float rs = 0.1767766953f;          // 1024^-0.25
  const float qs = rs * LOG2E;

  if (z == 2) {
    u16* tr = &SM[0][0][0][0];
    const int bb = (bm * 128) >> 11;
    const int t_base = (bm * 128) & (T_SEQ - 1);
#pragma unroll
    for (int hh = 0; hh < 2; ++hh) {
      __syncthreads();
      if (wn == hh) {
#pragma unroll
        for (int n = 0; n < 4; ++n) {
          float bv_ = bias[bn * 128 + wn * 64 + n * 16 + c];
#pragma unroll
          for (int m = 0; m < 4; ++m) {
#pragma unroll
            for (int i = 0; i < 4; ++i) {
              tr[(n * 16 + c) * 136 + wm * 64 + m * 16 + g * 4 + i] =
                  f2bf(acc[m][n][i] + bv_);
            }
          }
        }
      }
      __syncthreads();
#pragma unroll
      for (int rep = 0; rep < 4; ++rep) {
        int idx = tid + rep * 256;
        int dr = idx >> 4, ch = idx & 15;
        bf16x8 vv = *reinterpret_cast<const bf16x8*>(&tr[dr * 136 + ch * 8]);
        int d_glob = bn * 128 + hh * 64 + dr;
        int head = d_glob >> 6, dd = d_glob & 63;
        *reinterpret_cast<bf16x8*>(
            vt_ws + (((size_t)(bb * NHEAD + head) * HDIM + dd) * T_SEQ) + t_base + ch * 8) = vv;
      }
    }
  } else {
    u16* dst = (z == 0) ? q_ws : k_ws;
    const float sc = (z == 0) ? qs : rs;
#pragma unroll
    for (int m = 0; m < 4; ++m) {
      int mrow_base = bm * 128 + wm * 64 + m * 16 + g * 4;
#pragma unroll
      for (int n = 0; n < 4; ++n) {
        int n_idx = bn * 128 + wn * 64 + n * 16 + c;
        float bv_ = bias[n_idx];
        int head = n_idx >> 6, d = n_idx & 63;
#pragma unroll
        for (int i = 0; i < 4; ++i) {
          int mrow = mrow_base + i;
          int b = mrow >> 11, t = mrow & (T_SEQ - 1);
          dst[((size_t)(b * NHEAD + head) * T_SEQ + t) * HDIM + d] =
              f2bf((acc[m][n][i] + bv_) * sc);
        }
      }
    }
  }
}

// ---------------------------------------------------------------------------
// Flash attention r6 (verbatim): triangular-paired blocks, 33 kv-tiles each.
__global__ __launch_bounds__(256, 4) void attn_fused(
    const u16* __restrict__ Q, const u16* __restrict__ Kk,
    const u16* __restrict__ VT, u16* __restrict__ O)
{
  const int tid = threadIdx.x;
  const int w = tid >> 6;
  const int lane = tid & 63;
  const int g = lane >> 4, c = lane & 15;
  const int j = blockIdx.x;                    // 0..15 (pair index)
  const int bh = blockIdx.y;
  const int h = bh & (NHEAD - 1), b = bh >> 4;
  const float slope2 = exp2f(-0.5f * (float)(h + 1)) * LOG2E;
  const u16* Qp = Q  + (size_t)bh * T_SEQ * HDIM;
  const u16* Kp = Kk + (size_t)bh * T_SEQ * HDIM;
  const u16* Vp = VT + (size_t)bh * HDIM * T_SEQ;

  __shared__ u16 KB[2][64][64];
  __shared__ u16 VB[2][64][64];

  const int s_r0 = tid >> 3;          // 0..31
  const int s_r1 = s_r0 + 32;         // 32..63
  const int s_c0 = ((tid & 7) ^ (s_r0 & 7)) * 8;

  f32x4 zero4 = {0.f, 0.f, 0.f, 0.f};

  for (int pass = 0; pass < 2; ++pass) {
    const int qb = (pass == 0) ? (T_SEQ / 64 - 1 - j) : j;   // heavy then light
    const int q0 = qb * 64;
    const int qrow = q0 + w * 16;
    const int nt = qb + 1;

    bf16x8 qf0 = *reinterpret_cast<const bf16x8*>(Qp + (size_t)(qrow + c) * HDIM + g * 8);
    bf16x8 qf1 = *reinterpret_cast<const bf16x8*>(Qp + (size_t)(qrow + c) * HDIM + 32 + g * 8);

    {
      u16* kb = &KB[0][0][0]; u16* vb = &VB[0][0][0];
      gl_lds16(Kp + (size_t)(q0 + s_r0) * HDIM + s_c0, kb + tid * 8);
      gl_lds16(Kp + (size_t)(q0 + s_r1) * HDIM + s_c0, kb + (tid + 256) * 8);
      gl_lds16(Vp + (size_t)s_r0 * T_SEQ + q0 + s_c0, vb + tid * 8);
      gl_lds16(Vp + (size_t)s_r1 * T_SEQ + q0 + s_c0, vb + (tid + 256) * 8);
    }
    __syncthreads();

    f32x4 o[4];
#pragma unroll
    for (int dg = 0; dg < 4; ++dg) o[dg] = zero4;
    float mrun = -3.0e38f, lrun = 0.f;

    for (int t = 0; t < nt; ++t) {
      const u16* kb = &KB[t & 1][0][0];
      const u16* vb = &VB[t & 1][0][0];

      if (t + 1 < nt) {
        const int kvn = (nt - 2 - t) * 64;
        u16* kbn = &KB[(t + 1) & 1][0][0];
        u16* vbn = &VB[(t + 1) & 1][0][0];
        gl_lds16(Kp + (size_t)(kvn + s_r0) * HDIM + s_c0, kbn + tid * 8);
        gl_lds16(Kp + (size_t)(kvn + s_r1) * HDIM + s_c0, kbn + (tid + 256) * 8);
        gl_lds16(Vp + (size_t)s_r0 * T_SEQ + kvn + s_c0, vbn + tid * 8);
        gl_lds16(Vp + (size_t)s_r1 * T_SEQ + kvn + s_c0, vbn + (tid + 256) * 8);
      }

      const int kv0 = (nt - 1 - t) * 64;

      f32x4 s[4];
#pragma unroll
      for (int jj = 0; jj < 4; ++jj) {
        const int r = jj * 16 + c;
        bf16x8 k0 = *reinterpret_cast<const bf16x8*>(kb + r * 64 + ((g ^ (r & 7)) * 8));
        bf16x8 k1 = *reinterpret_cast<const bf16x8*>(kb + r * 64 + (((4 + g) ^ (r & 7)) * 8));
        f32x4 z4 = zero4;
        z4 = __builtin_amdgcn_mfma_f32_16x16x32_bf16(k0, qf0, z4, 0, 0, 0);
        z4 = __builtin_amdgcn_mfma_f32_16x16x32_bf16(k1, qf1, z4, 0, 0, 0);
        s[jj] = z4;
      }

      const int kbase = kv0 + 4 * g - (qrow + c);
      float mt = -3.0e38f;
      if (t == 0) {
#pragma unroll
        for (int jj = 0; jj < 4; ++jj)
#pragma unroll
          for (int i = 0; i < 4; ++i) {
            int rel = kbase + 16 * jj + i;
            float sv = s[jj][i] + slope2 * (float)rel;
            if (rel > 0) sv = -3.0e38f;
            s[jj][i] = sv;
            mt = fmaxf(mt, sv);
          }
      } else {
#pragma unroll
        for (int jj = 0; jj < 4; ++jj)
#pragma unroll
          for (int i = 0; i < 4; ++i) {
            float sv = s[jj][i] + slope2 * (float)(kbase + 16 * jj + i);
            s[jj][i] = sv;
            mt = fmaxf(mt, sv);
          }
      }
      mt = fmaxf(mt, __shfl_xor(mt, 16, 64));
      mt = fmaxf(mt, __shfl_xor(mt, 32, 64));

      if (!__all(mt <= mrun + 11.5416f)) {
        float mnew = fmaxf(mrun, mt);
        float alpha = __builtin_amdgcn_exp2f(mrun - mnew);
        mrun = mnew;
        lrun *= alpha;
        float ar[4];
#pragma unroll
        for (int i = 0; i < 4; ++i) ar[i] = __shfl(alpha, g * 4 + i, 64);
#pragma unroll
        for (int dg = 0; dg < 4; ++dg)
#pragma unroll
          for (int i = 0; i < 4; ++i) o[dg][i] *= ar[i];
      }

      float p[16];
      float rsum = 0.f;
#pragma unroll
      for (int jj = 0; jj < 4; ++jj)
#pragma unroll
        for (int i = 0; i < 4; ++i) {
          float e = __builtin_amdgcn_exp2f(s[jj][i] - mrun);
          rsum += e;
          p[jj * 4 + i] = e;
        }
      union { bf16x8 v; u32x4 u; } P0, P1;
#pragma unroll
      for (int k = 0; k < 4; ++k) {
        P0.u[k] = cvt_pk_bf16(p[2 * k], p[2 * k + 1]);
        P1.u[k] = cvt_pk_bf16(p[8 + 2 * k], p[8 + 2 * k + 1]);
      }
      rsum += __shfl_xor(rsum, 16, 64);
      rsum += __shfl_xor(rsum, 32, 64);
      lrun += rsum;

#pragma unroll
      for (int dg = 0; dg < 4; ++dg) {
        const int vr = dg * 16 + c;
        const int vbase = vr * 64 + (g & 1) * 4;
        const int sw = vr & 7;
        short4 a0 = *reinterpret_cast<const short4*>(vb + vbase + (((g >> 1) + 0) ^ sw) * 8);
        short4 a1 = *reinterpret_cast<const short4*>(vb + vbase + (((g >> 1) + 2) ^ sw) * 8);
        short4 a2 = *reinterpret_cast<const short4*>(vb + vbase + (((g >> 1) + 4) ^ sw) * 8);
        short4 a3 = *reinterpret_cast<const short4*>(vb + vbase + (((g >> 1) + 6) ^ sw) * 8);
        bf16x8 vf0, vf1;
#pragma unroll
        for (int e = 0; e < 4; ++e) {
          vf0[e] = a0[e]; vf0[4 + e] = a1[e];
          vf1[e] = a2[e]; vf1[4 + e] = a3[e];
        }
        o[dg] = __builtin_amdgcn_mfma_f32_16x16x32_bf16(P0.v, vf0, o[dg], 0, 0, 0);
        o[dg] = __builtin_amdgcn_mfma_f32_16x16x32_bf16(P1.v, vf1, o[dg], 0, 0, 0);
      }

      __syncthreads();
    }

    float rl[4];
#pragma unroll
    for (int i = 0; i < 4; ++i) {
      float li = __shfl(lrun, g * 4 + i, 64);
      rl[i] = 1.0f / li;
    }
#pragma unroll
    for (int dg = 0; dg < 4; ++dg) {
#pragma unroll
      for (int i = 0; i < 4; ++i) {
        int qi = qrow + g * 4 + i;
        O[((size_t)b * T_SEQ + qi) * DMODEL + h * HDIM + dg * 16 + c] =
            f2bf(o[dg][i] * rl[i]);
      }
    }
  }
}

// ---------------------------------------------------------------------------
// Output projection, r7: double-buffered 2-phase K-loop (same as qkv_gemm).
__global__ __launch_bounds__(256) void out_gemm(
    const u16* __restrict__ ao, const u16* __restrict__ wp,
    const float* __restrict__ bp, float* __restrict__ out)
{
  const int K = DMODEL;
  const int bm = blockIdx.y, bn = blockIdx.x;
  const int tid = threadIdx.x;
  const int w = tid >> 6, lane = tid & 63, g = lane >> 4, c = lane & 15;
  const int wm = w >> 1, wn = w & 1;

  __shared__ u16 SM[2][2][128][64];   // 64 KB

  f32x4 zero4 = {0.f, 0.f, 0.f, 0.f};
  f32x4 acc[4][4];
#pragma unroll
  for (int m = 0; m < 4; ++m)
#pragma unroll
    for (int n = 0; n < 4; ++n) acc[m][n] = zero4;

  int rr[4], cswz[4];
#pragma unroll
  for (int j = 0; j < 4; ++j) {
    int chunk = tid + 256 * j;
    rr[j] = chunk >> 3;
    cswz[j] = ((chunk & 7) ^ (rr[j] & 7)) * 8;
  }

  // prologue: stage k0=0 into buf 0
#pragma unroll
  for (int j = 0; j < 4; ++j) {
    int chunk = tid + 256 * j;
    gl_lds16(ao + (size_t)(bm * 128 + rr[j]) * K + cswz[j],
             &SM[0][0][0][0] + chunk * 8);
    gl_lds16(wp + (size_t)(bn * 128 + rr[j]) * K + cswz[j],
             &SM[0][1][0][0] + chunk * 8);
  }
  __syncthreads();

  for (int t = 0; t < 16; ++t) {
    const int buf = t & 1;
    if (t < 15) {
      const int k0 = (t + 1) * 64;
#pragma unroll
      for (int j = 0; j < 4; ++j) {
        int chunk = tid + 256 * j;
        gl_lds16(ao + (size_t)(bm * 128 + rr[j]) * K + k0 + cswz[j],
                 &SM[buf ^ 1][0][0][0] + chunk * 8);
        gl_lds16(wp + (size_t)(bn * 128 + rr[j]) * K + k0 + cswz[j],
                 &SM[buf ^ 1][1][0][0] + chunk * 8);
      }
    }
#pragma unroll
    for (int kk = 0; kk < 2; ++kk) {
      bf16x8 af[4], bfr[4];
#pragma unroll
      for (int m = 0; m < 4; ++m) {
        int row = wm * 64 + m * 16 + c;
        af[m] = *reinterpret_cast<const bf16x8*>(
            &SM[buf][0][row][(kk * 32 + g * 8) ^ ((row & 7) * 8)]);
      }
#pragma unroll
      for (int n = 0; n < 4; ++n) {
        int row = wn * 64 + n * 16 + c;
        bfr[n] = *reinterpret_cast<const bf16x8*>(
            &SM[buf][1][row][(kk * 32 + g * 8) ^ ((row & 7) * 8)]);
      }
#pragma unroll
      for (int m = 0; m < 4; ++m)
#pragma unroll
        for (int n = 0; n < 4; ++n)
          acc[m][n] = __builtin_amdgcn_mfma_f32_16x16x32_bf16(af[m], bfr[n], acc[m][n], 0, 0, 0);
    }
    __syncthreads();
  }

#pragma unroll
  for (int m = 0; m < 4; ++m) {
    int mrow_base = bm * 128 + wm * 64 + m * 16 + g * 4;
#pragma unroll
    for (int n = 0; n < 4; ++n) {
      int n_idx = bn * 128 + wn * 64 + n * 16 + c;
      float bv_ = bp[n_idx];
#pragma unroll
      for (int i = 0; i < 4; ++i) {
        int mrow = mrow_base + i;
        out[(size_t)mrow * DMODEL + n_idx] = acc[m][n][i] + bv_;
      }
    }
  }
}

// ---------------------------------------------------------------------------
extern "C" void kernel_launch(void* const* d_in, const int* in_sizes, int n_in,
                              void* d_out, int out_size, void* d_ws, size_t ws_size,
                              hipStream_t stream) {
  const float* x  = (const float*)d_in[0];
  const float* Wq = (const float*)d_in[1];
  const float* bq = (const float*)d_in[2];
  const float* Wk = (const float*)d_in[3];
  const float* bk = (const float*)d_in[4];
  const float* Wv = (const float*)d_in[5];
  const float* bv = (const float*)d_in[6];
  const float* Wp = (const float*)d_in[7];
  const float* bp = (const float*)d_in[8];
  float* out = (float*)d_out;

  u16* ws    = (u16*)d_ws;
  u16* xb    = ws;                       // 4,194,304  (x as bf16)
  u16* wqb   = xb   + 4194304;           // 4 x 1,048,576 contiguous
  u16* wkb   = wqb  + 1048576;
  u16* wvb   = wkb  + 1048576;
  u16* wpb   = wvb  + 1048576;
  u16* q_ws  = wpb  + 1048576;           // [B,NH,T,hd] (scaled by rs*log2e)
  u16* k_ws  = q_ws + 4194304;           // [B,NH,T,hd] (scaled by rs)
  u16* vt_ws = k_ws + 4194304;           // [B,NH,hd,T]
  u16* ao    = vt_ws + 4194304;          // [B,T,D] attention output

  cvt_bf16<<<4096, 256, 0, stream>>>(x, xb, 4194304);
  cvt_w4<<<dim3(1024, 4), 256, 0, stream>>>(Wq, Wk, Wv, Wp, wqb);

  qkv_gemm<<<dim3(DMODEL / 128, MROWS / 128, 3), 256, 0, stream>>>(
      xb, wqb, wkb, wvb, bq, bk, bv, q_ws, k_ws, vt_ws);

  attn_fused<<<dim3(T_SEQ / 128, 2 * NHEAD), 256, 0, stream>>>(q_ws, k_ws, vt_ws, ao);

  out_gemm<<<dim3(DMODEL / 128, MROWS / 128), 256, 0, stream>>>(ao, wpb, bp, out);
}